// Round 3
// baseline (1846.375 us; speedup 1.0000x reference)
//
#include <hip/hip_runtime.h>
#include <hip/hip_bf16.h>
#include <stdint.h>

// Sizes (fixed for this problem)
#define B_ 2
#define T_ 2048
#define H_ 1024
#define M_ 4096            // B*T
#define DI 2048
#define DS 128
#define CONVD 2304         // DI + 2*DS
#define LD2 4480           // in_proj out cols: 4384 padded to 128-multiple
#define EPS_ 1e-6f

typedef __bf16 bf16x8 __attribute__((ext_vector_type(8)));
typedef float f32x4 __attribute__((ext_vector_type(4)));
typedef uint32_t u32x4 __attribute__((ext_vector_type(4)));

__device__ __forceinline__ unsigned short f2bfu(float f) {
    union { float f; uint32_t u; } a; a.f = f;
    uint32_t r = a.u + 0x7FFFu + ((a.u >> 16) & 1u);
    return (unsigned short)(r >> 16);
}
__device__ __forceinline__ float bfu2f(unsigned short u) {
    union { uint32_t u; float f; } a; a.u = ((uint32_t)u) << 16; return a.f;
}
__device__ __forceinline__ float siluf(float x) { return x / (1.f + expf(-x)); }

// ---------------- RMS over 1024 cols -> bf16 ----------------
__global__ __launch_bounds__(256) void k_rms1024(const float* __restrict__ in, const float* __restrict__ w,
                                                 unsigned short* __restrict__ out) {
    __shared__ float red[4];
    int m = blockIdx.x, tid = threadIdx.x;
    size_t base = (size_t)m * H_ + tid * 4;
    float4 v = *(const float4*)(in + base);
    float ss = v.x * v.x + v.y * v.y + v.z * v.z + v.w * v.w;
#pragma unroll
    for (int off = 32; off; off >>= 1) ss += __shfl_xor(ss, off);
    if ((tid & 63) == 0) red[tid >> 6] = ss;
    __syncthreads();
    float scale = rsqrtf((red[0] + red[1] + red[2] + red[3]) * (1.f / 1024.f) + EPS_);
    float4 wv = *(const float4*)(w + tid * 4);
    ushort4 o;
    o.x = f2bfu(v.x * wv.x * scale); o.y = f2bfu(v.y * wv.y * scale);
    o.z = f2bfu(v.z * wv.z * scale); o.w = f2bfu(v.w * wv.w * scale);
    *(ushort4*)(out + base) = o;
}

// ---------------- transpose fp32 [K,N] -> bf16 [NP,K] (pad rows with 0) ----------------
__global__ __launch_bounds__(256) void k_transpose(const float* __restrict__ src, unsigned short* __restrict__ dst,
                                                   int K, int N, int NP) {
    __shared__ float t[32][33];
    int n0 = blockIdx.x * 32, k0 = blockIdx.y * 32;
    int tx = threadIdx.x & 31, ty = threadIdx.x >> 5;
#pragma unroll
    for (int i = ty; i < 32; i += 8) {
        int k = k0 + i, n = n0 + tx;
        t[i][tx] = (n < N) ? src[(size_t)k * N + n] : 0.f;
    }
    __syncthreads();
#pragma unroll
    for (int i = ty; i < 32; i += 8) {
        int n = n0 + i, k = k0 + tx;
        if (n < NP) dst[(size_t)n * K + k] = f2bfu(t[tx][i]);
    }
}

// ---------------- bf16 MFMA GEMM: C[M,N] = A[M,K] * Bt[N,K]^T, templated epilogue ----------
// EPI: 0 = f32 store, 1 = bf16 store, 2 = silu->bf16, 3 = exp(-exp)->f32, 4 = gelu->bf16
template <int EPI>
__global__ __launch_bounds__(256) void k_gemm(const unsigned short* __restrict__ A, const unsigned short* __restrict__ Bt,
                                              void* __restrict__ Cout, int M, int N, int K) {
    __shared__ alignas(16) unsigned short As[128 * 64];
    __shared__ alignas(16) unsigned short Bs[128 * 64];
    const int tid = threadIdx.x;
    const int m0 = blockIdx.y * 128, n0 = blockIdx.x * 128;
    const int wave = tid >> 6, lane = tid & 63;
    const int wm = (wave >> 1) * 64, wn = (wave & 1) * 64;
    const int fr = lane & 15, fg = lane >> 4;
    const int srow = tid >> 3;        // 0..31 (+32 per chunk)
    const int ske = (tid & 7) * 8;    // element offset of this thread's 16B chunk

    f32x4 acc[4][4];
#pragma unroll
    for (int m = 0; m < 4; m++)
#pragma unroll
        for (int n = 0; n < 4; n++) acc[m][n] = (f32x4)(0.f);

    const int nk = K >> 6;
    u32x4 ra[4], rb[4];
#pragma unroll
    for (int i = 0; i < 4; i++) {
        ra[i] = *(const u32x4*)(A + (size_t)(m0 + srow + 32 * i) * K + ske);
        rb[i] = *(const u32x4*)(Bt + (size_t)(n0 + srow + 32 * i) * K + ske);
    }
    for (int kt = 0; kt < nk; ++kt) {
        __syncthreads();
#pragma unroll
        for (int i = 0; i < 4; i++) {
            int lin = (tid + 256 * i) * 16;
            int sw = lin ^ (((lin >> 7) & 7) << 4);
            *(u32x4*)((char*)As + sw) = ra[i];
            *(u32x4*)((char*)Bs + sw) = rb[i];
        }
        __syncthreads();
        if (kt + 1 < nk) {
#pragma unroll
            for (int i = 0; i < 4; i++) {
                ra[i] = *(const u32x4*)(A + (size_t)(m0 + srow + 32 * i) * K + (kt + 1) * 64 + ske);
                rb[i] = *(const u32x4*)(Bt + (size_t)(n0 + srow + 32 * i) * K + (kt + 1) * 64 + ske);
            }
        }
#pragma unroll
        for (int ks = 0; ks < 2; ++ks) {
            bf16x8 af[4], bg[4];
#pragma unroll
            for (int m = 0; m < 4; m++) {
                int row = wm + m * 16 + fr;
                int lin = row * 128 + ks * 64 + fg * 16;
                af[m] = *(const bf16x8*)((const char*)As + (lin ^ ((row & 7) << 4)));
            }
#pragma unroll
            for (int n = 0; n < 4; n++) {
                int col = wn + n * 16 + fr;
                int lin = col * 128 + ks * 64 + fg * 16;
                bg[n] = *(const bf16x8*)((const char*)Bs + (lin ^ ((col & 7) << 4)));
            }
#pragma unroll
            for (int m = 0; m < 4; m++)
#pragma unroll
                for (int n = 0; n < 4; n++)
                    acc[m][n] = __builtin_amdgcn_mfma_f32_16x16x32_bf16(af[m], bg[n], acc[m][n], 0, 0, 0);
        }
    }
#pragma unroll
    for (int m = 0; m < 4; m++) {
#pragma unroll
        for (int r = 0; r < 4; r++) {
            size_t row = (size_t)(m0 + wm + m * 16 + fg * 4 + r);
#pragma unroll
            for (int n = 0; n < 4; n++) {
                size_t idx = row * N + n0 + wn + n * 16 + fr;
                float v = acc[m][n][r];
                if constexpr (EPI == 0) ((float*)Cout)[idx] = v;
                else if constexpr (EPI == 1) ((unsigned short*)Cout)[idx] = f2bfu(v);
                else if constexpr (EPI == 2) ((unsigned short*)Cout)[idx] = f2bfu(siluf(v));
                else if constexpr (EPI == 3) ((float*)Cout)[idx] = expf(-expf(v));
                else ((unsigned short*)Cout)[idx] = f2bfu(0.5f * v * (1.f + erff(v * 0.70710678118f)));
            }
        }
    }
}

// ---------------- RWKV sequential scan ----------------
// grid (32 vblocks, 8 bh), 256 thr. wave w: k in [64w,64w+64); lane=(kq<<3)|vv; lane owns 8 k x 1 v.
#define RT 16
__global__ __launch_bounds__(256) void k_rwkv_scan(const unsigned short* __restrict__ RB, const unsigned short* __restrict__ KB,
                                                   const unsigned short* __restrict__ VB, const float* __restrict__ WF,
                                                   const float* __restrict__ u, float* __restrict__ o) {
    __shared__ float lr[RT][256], lk[RT][256], lw[RT][256];
    __shared__ float lv[RT][8];
    __shared__ float pbuf[RT][4][8];
    const int tid = threadIdx.x;
    const int bh = blockIdx.y;
    const int b = bh >> 2, h = bh & 3;
    const int v0 = blockIdx.x * 8;
    const int wave = tid >> 6, lane = tid & 63;
    const int kq = lane >> 3, vv = lane & 7;
    const int K0 = wave * 64 + kq * 8;
    const size_t baseM = (size_t)b * T_;
    float S[8] = {0.f, 0.f, 0.f, 0.f, 0.f, 0.f, 0.f, 0.f};
    float ureg[8];
#pragma unroll
    for (int i = 0; i < 8; i++) ureg[i] = u[h * 256 + K0 + i];

    for (int c = 0; c < T_ / RT; ++c) {
        __syncthreads();
        if (c > 0 && tid < RT * 8) {
            int tt = tid >> 3, xx = tid & 7;
            size_t m = baseM + (size_t)(c - 1) * RT + tt;
            o[m * H_ + h * 256 + v0 + xx] = pbuf[tt][0][xx] + pbuf[tt][1][xx] + pbuf[tt][2][xx] + pbuf[tt][3][xx];
        }
        int t0 = c * RT;
#pragma unroll
        for (int it = 0; it < 4; ++it) {
            int idx = (tid + it * 256) * 4;   // 0..4092 over RT*256
            int tt = idx >> 8, k = idx & 255;
            size_t rowb = (baseM + t0 + tt) * H_ + h * 256 + k;
            ushort4 r4 = *(const ushort4*)(RB + rowb);
            ushort4 k4 = *(const ushort4*)(KB + rowb);
            float4 w4 = *(const float4*)(WF + rowb);
            lr[tt][k] = bfu2f(r4.x); lr[tt][k + 1] = bfu2f(r4.y); lr[tt][k + 2] = bfu2f(r4.z); lr[tt][k + 3] = bfu2f(r4.w);
            lk[tt][k] = bfu2f(k4.x); lk[tt][k + 1] = bfu2f(k4.y); lk[tt][k + 2] = bfu2f(k4.z); lk[tt][k + 3] = bfu2f(k4.w);
            lw[tt][k] = w4.x; lw[tt][k + 1] = w4.y; lw[tt][k + 2] = w4.z; lw[tt][k + 3] = w4.w;
        }
        if (tid < RT * 8) {
            int tt = tid >> 3, xx = tid & 7;
            lv[tt][xx] = bfu2f(VB[(baseM + t0 + tt) * H_ + h * 256 + v0 + xx]);
        }
        __syncthreads();
#pragma unroll 1
        for (int tt = 0; tt < RT; ++tt) {
            float vt = lv[tt][vv];
            float p = 0.f, dsum = 0.f;
#pragma unroll
            for (int i = 0; i < 8; i++) {
                float rr = lr[tt][K0 + i];
                float kk = lk[tt][K0 + i];
                float ww = lw[tt][K0 + i];
                p = fmaf(rr, S[i], p);               // uses S_{t-1}
                dsum = fmaf(rr * ureg[i], kk, dsum);
                S[i] = fmaf(S[i], ww, kk * vt);
            }
            p = fmaf(dsum, vt, p);
            p += __shfl_xor(p, 8);
            p += __shfl_xor(p, 16);
            p += __shfl_xor(p, 32);
            if (kq == 0) pbuf[tt][wave][vv] = p;
        }
    }
    __syncthreads();
    if (tid < RT * 8) {
        int tt = tid >> 3, xx = tid & 7;
        size_t m = baseM + (size_t)(T_ - RT) + tt;
        o[m * H_ + h * 256 + v0 + xx] = pbuf[tt][0][xx] + pbuf[tt][1][xx] + pbuf[tt][2][xx] + pbuf[tt][3][xx];
    }
}

// ---------------- RWKV post: per-head RMS * gn_w * g -> bf16 (in place over g) ----------------
__global__ __launch_bounds__(256) void k_rwkv_post(const float* __restrict__ o, const float* __restrict__ gn_w,
                                                   unsigned short* __restrict__ g_io) {
    int m = blockIdx.x, tid = threadIdx.x;
    int wave = tid >> 6, lane = tid & 63;
    size_t base = (size_t)m * H_ + wave * 256 + lane * 4;
    int col = wave * 256 + lane * 4;
    float4 v = *(const float4*)(o + base);
    float ss = v.x * v.x + v.y * v.y + v.z * v.z + v.w * v.w;
#pragma unroll
    for (int off = 32; off; off >>= 1) ss += __shfl_xor(ss, off);
    float scale = rsqrtf(ss * (1.f / 256.f) + EPS_);
    float4 gn = *(const float4*)(gn_w + col);
    ushort4 gb4 = *(const ushort4*)(g_io + base);
    ushort4 out;
    out.x = f2bfu(v.x * scale * gn.x * bfu2f(gb4.x));
    out.y = f2bfu(v.y * scale * gn.y * bfu2f(gb4.y));
    out.z = f2bfu(v.z * scale * gn.z * bfu2f(gb4.z));
    out.w = f2bfu(v.w * scale * gn.w * bfu2f(gb4.w));
    *(ushort4*)(g_io + base) = out;
}

// ---------------- causal depthwise conv(4) + bias + silu (bf16 in, split out) ----------------
__global__ __launch_bounds__(256) void k_conv(const unsigned short* __restrict__ C2B, const float* __restrict__ conv_w,
                                              const float* __restrict__ conv_b, unsigned short* __restrict__ XB,
                                              float* __restrict__ BCF) {
    int m = blockIdx.y;
    int c = blockIdx.x * 256 + threadIdx.x;  // < 2304
    int b = m >> 11, t = m & 2047;
    float acc = conv_b[c];
#pragma unroll
    for (int i = 0; i < 4; i++) {
        int tt = t - 3 + i;
        if (tt >= 0) acc = fmaf(bfu2f(C2B[((size_t)(b * T_ + tt)) * LD2 + DI + c]), conv_w[c * 4 + i], acc);
    }
    float r = siluf(acc);
    if (c < DI) XB[(size_t)m * DI + c] = f2bfu(r);
    else BCF[(size_t)m * 256 + (c - DI)] = r;
}

// ---------------- Mamba sequential scan ----------------
// grid (4 dquads, 64 bh), 256 thr. wave w: d in [d0+4w, d0+4w+4); lane=(sq<<2)|dd; lane owns 8 s x 1 d.
#define MT 32
__global__ __launch_bounds__(256) void k_mamba_scan(const unsigned short* __restrict__ C2B, const unsigned short* __restrict__ XB,
                                                    const float* __restrict__ BCF,
                                                    const float* __restrict__ dt_bias, const float* __restrict__ A_log,
                                                    unsigned short* __restrict__ y) {
    __shared__ float lB[MT][128], lC[MT][128], lx[MT][16], lda[MT], ldt[MT];
    const int tid = threadIdx.x;
    const int bh = blockIdx.y;
    const int b = bh >> 5, h = bh & 31;
    const int d0 = blockIdx.x * 16;
    const int wave = tid >> 6, lane = tid & 63;
    const int sq = lane >> 2, dd = lane & 3;
    const int S0 = sq * 8;
    const size_t baseM = (size_t)b * T_;
    const float A = -expf(A_log[h]);
    const float dtb = dt_bias[h];
    float hS[8] = {0.f, 0.f, 0.f, 0.f, 0.f, 0.f, 0.f, 0.f};

    for (int c = 0; c < T_ / MT; ++c) {
        __syncthreads();
        int t0 = c * MT;
#pragma unroll
        for (int it = 0; it < 8; ++it) {       // MT*256 = 8192 floats: 8 x 256thr x float4
            int idx = (tid + it * 256) * 4;
            int tt = idx >> 8, s2 = idx & 255;  // s2 in [0,256): 0..127 -> B, 128..255 -> C
            float4 v4 = *(const float4*)(BCF + (baseM + t0 + tt) * 256 + s2);
            if (s2 < 128) { lB[tt][s2] = v4.x; lB[tt][s2 + 1] = v4.y; lB[tt][s2 + 2] = v4.z; lB[tt][s2 + 3] = v4.w; }
            else { int s = s2 - 128; lC[tt][s] = v4.x; lC[tt][s + 1] = v4.y; lC[tt][s + 2] = v4.z; lC[tt][s + 3] = v4.w; }
        }
#pragma unroll
        for (int it = 0; it < 2; ++it) {
            int idx = tid + it * 256;          // 0..511 over MT*16
            int tt = idx >> 4, i = idx & 15;
            lx[tt][i] = bfu2f(XB[(baseM + t0 + tt) * DI + h * 64 + d0 + i]);
        }
        if (tid < MT) {
            float draw = bfu2f(C2B[(baseM + t0 + tid) * LD2 + 4352 + h]) + dtb;
            float ds = draw > 20.f ? draw : log1pf(expf(draw));
            ldt[tid] = ds;
            lda[tid] = expf(A * ds);
        }
        __syncthreads();
#pragma unroll 1
        for (int tt = 0; tt < MT; ++tt) {
            float da = lda[tt];
            float dtx = ldt[tt] * lx[tt][wave * 4 + dd];
            float p = 0.f;
#pragma unroll
            for (int i = 0; i < 8; i++) {
                float Bv = lB[tt][S0 + i];
                float Cv = lC[tt][S0 + i];
                hS[i] = fmaf(hS[i], da, dtx * Bv);
                p = fmaf(hS[i], Cv, p);  // y uses updated h
            }
            p += __shfl_xor(p, 4);
            p += __shfl_xor(p, 8);
            p += __shfl_xor(p, 16);
            p += __shfl_xor(p, 32);
            if (sq == 0) y[(baseM + t0 + tt) * DI + h * 64 + d0 + wave * 4 + dd] = f2bfu(p);
        }
    }
}

// ---------------- Mamba post: (y + D*x) * silu(z), RMS(2048) * m_norm_w -> bf16 in place over y ----
__global__ __launch_bounds__(256) void k_mamba_post(unsigned short* __restrict__ y_io, const unsigned short* __restrict__ XB,
                                                    const unsigned short* __restrict__ C2B, const float* __restrict__ D_m,
                                                    const float* __restrict__ mnw) {
    __shared__ float red[4];
    int m = blockIdx.x, tid = threadIdx.x;
    int j0 = tid * 8;
    const float Dv = D_m[j0 >> 6];
    ushort4 ya = *(const ushort4*)(y_io + (size_t)m * DI + j0);
    ushort4 yb = *(const ushort4*)(y_io + (size_t)m * DI + j0 + 4);
    ushort4 xa = *(const ushort4*)(XB + (size_t)m * DI + j0);
    ushort4 xb = *(const ushort4*)(XB + (size_t)m * DI + j0 + 4);
    ushort4 za = *(const ushort4*)(C2B + (size_t)m * LD2 + j0);
    ushort4 zb = *(const ushort4*)(C2B + (size_t)m * LD2 + j0 + 4);
    float yv[8] = {bfu2f(ya.x), bfu2f(ya.y), bfu2f(ya.z), bfu2f(ya.w), bfu2f(yb.x), bfu2f(yb.y), bfu2f(yb.z), bfu2f(yb.w)};
    float xv[8] = {bfu2f(xa.x), bfu2f(xa.y), bfu2f(xa.z), bfu2f(xa.w), bfu2f(xb.x), bfu2f(xb.y), bfu2f(xb.z), bfu2f(xb.w)};
    float zv[8] = {bfu2f(za.x), bfu2f(za.y), bfu2f(za.z), bfu2f(za.w), bfu2f(zb.x), bfu2f(zb.y), bfu2f(zb.z), bfu2f(zb.w)};
    float val[8];
    float ss = 0.f;
#pragma unroll
    for (int i = 0; i < 8; i++) {
        float v = (yv[i] + Dv * xv[i]) * siluf(zv[i]);
        val[i] = v;
        ss += v * v;
    }
#pragma unroll
    for (int off = 32; off; off >>= 1) ss += __shfl_xor(ss, off);
    if ((tid & 63) == 0) red[tid >> 6] = ss;
    __syncthreads();
    float scale = rsqrtf((red[0] + red[1] + red[2] + red[3]) * (1.f / 2048.f) + EPS_);
    ushort4 oa, ob;
    oa.x = f2bfu(val[0] * scale * mnw[j0 + 0]); oa.y = f2bfu(val[1] * scale * mnw[j0 + 1]);
    oa.z = f2bfu(val[2] * scale * mnw[j0 + 2]); oa.w = f2bfu(val[3] * scale * mnw[j0 + 3]);
    ob.x = f2bfu(val[4] * scale * mnw[j0 + 4]); ob.y = f2bfu(val[5] * scale * mnw[j0 + 5]);
    ob.z = f2bfu(val[6] * scale * mnw[j0 + 6]); ob.w = f2bfu(val[7] * scale * mnw[j0 + 7]);
    *(ushort4*)(y_io + (size_t)m * DI + j0) = oa;
    *(ushort4*)(y_io + (size_t)m * DI + j0 + 4) = ob;
}

// ---------------- gate + mix + residual + RMS(ffn_ln) -> x1 f32, nx2 bf16 ----------------
__global__ __launch_bounds__(256) void k_mix(const float* __restrict__ x, const float* __restrict__ o_r,
                                             const float* __restrict__ o_m, const float* __restrict__ gw,
                                             const float* __restrict__ gb, const float* __restrict__ flnw,
                                             float* __restrict__ x1, unsigned short* __restrict__ nx2) {
    __shared__ float red[4];
    int m = blockIdx.x, tid = threadIdx.x;
    size_t base = (size_t)m * H_ + tid * 4;
    float4 orv = *(const float4*)(o_r + base);
    float4 omv = *(const float4*)(o_m + base);
    float4 xv = *(const float4*)(x + base);
    float4 g1 = *(const float4*)(gw + tid * 4);
    float4 g2 = *(const float4*)(gw + 1024 + tid * 4);
    float ps = orv.x * g1.x + orv.y * g1.y + orv.z * g1.z + orv.w * g1.w
             + omv.x * g2.x + omv.y * g2.y + omv.z * g2.z + omv.w * g2.w;
#pragma unroll
    for (int off = 32; off; off >>= 1) ps += __shfl_xor(ps, off);
    if ((tid & 63) == 0) red[tid >> 6] = ps;
    __syncthreads();
    float g = 1.f / (1.f + expf(-(red[0] + red[1] + red[2] + red[3] + gb[0])));
    float4 xo;
    xo.x = xv.x + g * orv.x + (1.f - g) * omv.x;
    xo.y = xv.y + g * orv.y + (1.f - g) * omv.y;
    xo.z = xv.z + g * orv.z + (1.f - g) * omv.z;
    xo.w = xv.w + g * orv.w + (1.f - g) * omv.w;
    *(float4*)(x1 + base) = xo;
    float ss = xo.x * xo.x + xo.y * xo.y + xo.z * xo.z + xo.w * xo.w;
#pragma unroll
    for (int off = 32; off; off >>= 1) ss += __shfl_xor(ss, off);
    __syncthreads();
    if ((tid & 63) == 0) red[tid >> 6] = ss;
    __syncthreads();
    float scale = rsqrtf((red[0] + red[1] + red[2] + red[3]) * (1.f / 1024.f) + EPS_);
    float4 wv = *(const float4*)(flnw + tid * 4);
    ushort4 o;
    o.x = f2bfu(xo.x * scale * wv.x); o.y = f2bfu(xo.y * scale * wv.y);
    o.z = f2bfu(xo.z * scale * wv.z); o.w = f2bfu(xo.w * scale * wv.w);
    *(ushort4*)(nx2 + base) = o;
}

// ---------------- final residual add ----------------
__global__ __launch_bounds__(256) void k_final(const float* __restrict__ x1, const float* __restrict__ f,
                                               float* __restrict__ out) {
    size_t i4 = ((size_t)blockIdx.x * 256 + threadIdx.x) * 4;
    float4 a = *(const float4*)(x1 + i4);
    float4 b = *(const float4*)(f + i4);
    float4 r; r.x = a.x + b.x; r.y = a.y + b.y; r.z = a.z + b.z; r.w = a.w + b.w;
    *(float4*)(out + i4) = r;
}

extern "C" void kernel_launch(void* const* d_in, const int* in_sizes, int n_in,
                              void* d_out, int out_size, void* d_ws, size_t ws_size,
                              hipStream_t stream) {
    const float* x = (const float*)d_in[0];
    const float* ln_w = (const float*)d_in[1];
    const float* r_w = (const float*)d_in[2];
    const float* k_w = (const float*)d_in[3];
    const float* v_w = (const float*)d_in[4];
    const float* g_w = (const float*)d_in[5];
    const float* dw_w = (const float*)d_in[6];
    const float* u = (const float*)d_in[7];
    const float* gn_w = (const float*)d_in[8];
    const float* o_w = (const float*)d_in[9];
    const float* in_proj = (const float*)d_in[10];
    const float* conv_w = (const float*)d_in[11];
    const float* conv_b = (const float*)d_in[12];
    const float* dt_bias = (const float*)d_in[13];
    const float* A_log = (const float*)d_in[14];
    const float* D_m = (const float*)d_in[15];
    const float* m_norm_w = (const float*)d_in[16];
    const float* out_proj = (const float*)d_in[17];
    const float* gate_w = (const float*)d_in[18];
    const float* gate_b = (const float*)d_in[19];
    const float* ffn_ln_w = (const float*)d_in[20];
    const float* ffn_w1 = (const float*)d_in[21];
    const float* ffn_w2 = (const float*)d_in[22];
    (void)in_sizes; (void)n_in;

    // ---- explicit workspace layout (peak ~184 MiB) ----
    const size_t NEEDED = 192675840ull;
    if (ws_size < NEEDED) {  // diagnostic fallback: clean zeros instead of OOB crash
        hipMemsetAsync(d_out, 0, (size_t)out_size * 4, stream);
        return;
    }
    char* ws = (char*)d_ws;
    unsigned short* WT5 = (unsigned short*)(ws + 0);            // 5 x [1024][1024] bf16 = 10,485,760
    unsigned short* INPT = (unsigned short*)(ws + 10485760);    // [4480][1024] bf16 = 9,175,040
    unsigned short* F1T = (unsigned short*)(ws + 0);            // overlay (after big GEMMs): [4096][1024] bf16
    unsigned short* F2T = (unsigned short*)(ws + 10485760);     // overlay: [1024][4096] bf16
    unsigned short* OWT = (unsigned short*)(ws + 19660800);     // [1024][1024] bf16 = 2,097,152
    unsigned short* OPT = (unsigned short*)(ws + 21757952);     // [1024][2048] bf16 = 4,194,304
    unsigned short* NXB = (unsigned short*)(ws + 25952256);     // [4096][1024] bf16 (nx; later nx2)
    unsigned short* RB = (unsigned short*)(ws + 34340864);      // [4096][1024] bf16
    unsigned short* KB = (unsigned short*)(ws + 42729472);      // [4096][1024] bf16
    unsigned short* VB = (unsigned short*)(ws + 51118080);      // [4096][1024] bf16
    unsigned short* GB = (unsigned short*)(ws + 59506688);      // [4096][1024] bf16 silu(g); in-place -> o*gn*g
    float* WF = (float*)(ws + 67895296);                        // [4096][1024] f32 decay
    float* OM = (float*)(ws + 34340864);                        // overlay RB/KB (dead after scan): o_m f32 16,777,216
    unsigned short* MIDB = (unsigned short*)(ws + 51118080);    // overlay VB/GB/WF: [4096][4096] bf16 = 33,554,432
    unsigned short* C2B = (unsigned short*)(ws + 84672512);     // [4096][4480] bf16 = 36,700,160
    unsigned short* XB = (unsigned short*)(ws + 121372672);     // [4096][2048] bf16 conv-x
    float* BCF = (float*)(ws + 138149888);                      // [4096][256] f32 conv-B|C
    float* OBUF = (float*)(ws + 142344192);                     // [4096][1024] f32 rwkv o; later x1
    float* ORB = (float*)(ws + 159121408);                      // [4096][1024] f32 o_r; later ffn out
    unsigned short* YB = (unsigned short*)(ws + 175898624);     // [4096][2048] bf16 y; in-place gated-rms
    // end: 192,675,840

    dim3 blk(256);
    // nx = rms(x, ln_w) -> bf16
    k_rms1024<<<M_, blk, 0, stream>>>(x, ln_w, NXB);
    // weight transposes (fp32 [K,N] -> bf16 [NP,K])
    k_transpose<<<dim3(32, 32), blk, 0, stream>>>(r_w, WT5 + 0ull * 1048576, 1024, 1024, 1024);
    k_transpose<<<dim3(32, 32), blk, 0, stream>>>(k_w, WT5 + 1ull * 1048576, 1024, 1024, 1024);
    k_transpose<<<dim3(32, 32), blk, 0, stream>>>(v_w, WT5 + 2ull * 1048576, 1024, 1024, 1024);
    k_transpose<<<dim3(32, 32), blk, 0, stream>>>(g_w, WT5 + 3ull * 1048576, 1024, 1024, 1024);
    k_transpose<<<dim3(32, 32), blk, 0, stream>>>(dw_w, WT5 + 4ull * 1048576, 1024, 1024, 1024);
    k_transpose<<<dim3(140, 32), blk, 0, stream>>>(in_proj, INPT, 1024, 4384, 4480);
    k_transpose<<<dim3(32, 32), blk, 0, stream>>>(o_w, OWT, 1024, 1024, 1024);
    k_transpose<<<dim3(32, 64), blk, 0, stream>>>(out_proj, OPT, 2048, 1024, 1024);
    // projections with fused epilogues
    k_gemm<1><<<dim3(8, 32), blk, 0, stream>>>(NXB, WT5 + 0ull * 1048576, RB, 4096, 1024, 1024);
    k_gemm<1><<<dim3(8, 32), blk, 0, stream>>>(NXB, WT5 + 1ull * 1048576, KB, 4096, 1024, 1024);
    k_gemm<1><<<dim3(8, 32), blk, 0, stream>>>(NXB, WT5 + 2ull * 1048576, VB, 4096, 1024, 1024);
    k_gemm<2><<<dim3(8, 32), blk, 0, stream>>>(NXB, WT5 + 3ull * 1048576, GB, 4096, 1024, 1024);
    k_gemm<3><<<dim3(8, 32), blk, 0, stream>>>(NXB, WT5 + 4ull * 1048576, WF, 4096, 1024, 1024);
    k_gemm<1><<<dim3(35, 32), blk, 0, stream>>>(NXB, INPT, C2B, 4096, 4480, 1024);
    // FFN weight transposes AFTER big GEMMs (overlay WT5/INPT region)
    k_transpose<<<dim3(128, 32), blk, 0, stream>>>(ffn_w1, F1T, 1024, 4096, 4096);
    k_transpose<<<dim3(32, 128), blk, 0, stream>>>(ffn_w2, F2T, 4096, 1024, 1024);
    // conv + scans
    k_conv<<<dim3(9, M_), blk, 0, stream>>>(C2B, conv_w, conv_b, XB, BCF);
    k_rwkv_scan<<<dim3(32, 8), blk, 0, stream>>>(RB, KB, VB, WF, u, OBUF);
    k_mamba_scan<<<dim3(4, 64), blk, 0, stream>>>(C2B, XB, BCF, dt_bias, A_log, YB);
    // rwkv output path
    k_rwkv_post<<<M_, blk, 0, stream>>>(OBUF, gn_w, GB);
    k_gemm<0><<<dim3(8, 32), blk, 0, stream>>>(GB, OWT, ORB, 4096, 1024, 1024);
    // mamba output path
    k_mamba_post<<<M_, blk, 0, stream>>>(YB, XB, C2B, D_m, m_norm_w);
    k_gemm<0><<<dim3(8, 32), blk, 0, stream>>>(YB, OPT, OM, 4096, 1024, 2048);
    // gate + residual + ffn rms (x1 over OBUF, nx2 over NXB)
    k_mix<<<M_, blk, 0, stream>>>(x, ORB, OM, gate_w, gate_b, ffn_ln_w, OBUF, NXB);
    // FFN: mid written as gelu(bf16) directly; out over ORB
    k_gemm<4><<<dim3(32, 32), blk, 0, stream>>>(NXB, F1T, MIDB, 4096, 4096, 1024);
    k_gemm<0><<<dim3(8, 32), blk, 0, stream>>>(MIDB, F2T, ORB, 4096, 1024, 4096);
    k_final<<<M_, blk, 0, stream>>>(OBUF, ORB, (float*)d_out);
}

// Round 4
// 1219.461 us; speedup vs baseline: 1.5141x; 1.5141x over previous
//
#include <hip/hip_runtime.h>
#include <hip/hip_bf16.h>
#include <stdint.h>

// Sizes (fixed for this problem)
#define B_ 2
#define T_ 2048
#define H_ 1024
#define M_ 4096            // B*T
#define DI 2048
#define DS 128
#define CONVD 2304         // DI + 2*DS
#define LD2 4480           // in_proj out cols: 4384 padded to 128-multiple
#define EPS_ 1e-6f

typedef __bf16 bf16x8 __attribute__((ext_vector_type(8)));
typedef float f32x4 __attribute__((ext_vector_type(4)));
typedef uint32_t u32x4 __attribute__((ext_vector_type(4)));

__device__ __forceinline__ unsigned short f2bfu(float f) {
    union { float f; uint32_t u; } a; a.f = f;
    uint32_t r = a.u + 0x7FFFu + ((a.u >> 16) & 1u);
    return (unsigned short)(r >> 16);
}
__device__ __forceinline__ float bfu2f(unsigned short u) {
    union { uint32_t u; float f; } a; a.u = ((uint32_t)u) << 16; return a.f;
}
__device__ __forceinline__ float siluf(float x) { return x / (1.f + expf(-x)); }

// ---------------- RMS over 1024 cols -> bf16 ----------------
__global__ __launch_bounds__(256) void k_rms1024(const float* __restrict__ in, const float* __restrict__ w,
                                                 unsigned short* __restrict__ out) {
    __shared__ float red[4];
    int m = blockIdx.x, tid = threadIdx.x;
    size_t base = (size_t)m * H_ + tid * 4;
    float4 v = *(const float4*)(in + base);
    float ss = v.x * v.x + v.y * v.y + v.z * v.z + v.w * v.w;
#pragma unroll
    for (int off = 32; off; off >>= 1) ss += __shfl_xor(ss, off);
    if ((tid & 63) == 0) red[tid >> 6] = ss;
    __syncthreads();
    float scale = rsqrtf((red[0] + red[1] + red[2] + red[3]) * (1.f / 1024.f) + EPS_);
    float4 wv = *(const float4*)(w + tid * 4);
    ushort4 o;
    o.x = f2bfu(v.x * wv.x * scale); o.y = f2bfu(v.y * wv.y * scale);
    o.z = f2bfu(v.z * wv.z * scale); o.w = f2bfu(v.w * wv.w * scale);
    *(ushort4*)(out + base) = o;
}

// ---------------- transpose fp32 [K,N] -> bf16 [NP,K] (pad rows with 0) ----------------
__global__ __launch_bounds__(256) void k_transpose(const float* __restrict__ src, unsigned short* __restrict__ dst,
                                                   int K, int N, int NP) {
    __shared__ float t[32][33];
    int n0 = blockIdx.x * 32, k0 = blockIdx.y * 32;
    int tx = threadIdx.x & 31, ty = threadIdx.x >> 5;
#pragma unroll
    for (int i = ty; i < 32; i += 8) {
        int k = k0 + i, n = n0 + tx;
        t[i][tx] = (n < N) ? src[(size_t)k * N + n] : 0.f;
    }
    __syncthreads();
#pragma unroll
    for (int i = ty; i < 32; i += 8) {
        int n = n0 + i, k = k0 + tx;
        if (n < NP) dst[(size_t)n * K + k] = f2bfu(t[tx][i]);
    }
}

// ---------------- bf16 MFMA GEMM: C[M,N] = A[M,K] * Bt[N,K]^T, templated epilogue ----------
// EPI: 0 = f32 store, 4 = gelu->bf16, 5 = f32 store of (v + aux) [residual fusion]
template <int EPI>
__global__ __launch_bounds__(256) void k_gemm(const unsigned short* __restrict__ A, const unsigned short* __restrict__ Bt,
                                              void* __restrict__ Cout, const float* __restrict__ aux,
                                              int M, int N, int K) {
    __shared__ alignas(16) unsigned short As[128 * 64];
    __shared__ alignas(16) unsigned short Bs[128 * 64];
    const int tid = threadIdx.x;
    const int m0 = blockIdx.y * 128, n0 = blockIdx.x * 128;
    const int wave = tid >> 6, lane = tid & 63;
    const int wm = (wave >> 1) * 64, wn = (wave & 1) * 64;
    const int fr = lane & 15, fg = lane >> 4;
    const int srow = tid >> 3;
    const int ske = (tid & 7) * 8;

    f32x4 acc[4][4];
#pragma unroll
    for (int m = 0; m < 4; m++)
#pragma unroll
        for (int n = 0; n < 4; n++) acc[m][n] = (f32x4)(0.f);

    const int nk = K >> 6;
    u32x4 ra[4], rb[4];
#pragma unroll
    for (int i = 0; i < 4; i++) {
        ra[i] = *(const u32x4*)(A + (size_t)(m0 + srow + 32 * i) * K + ske);
        rb[i] = *(const u32x4*)(Bt + (size_t)(n0 + srow + 32 * i) * K + ske);
    }
    for (int kt = 0; kt < nk; ++kt) {
        __syncthreads();
#pragma unroll
        for (int i = 0; i < 4; i++) {
            int lin = (tid + 256 * i) * 16;
            int sw = lin ^ (((lin >> 7) & 7) << 4);
            *(u32x4*)((char*)As + sw) = ra[i];
            *(u32x4*)((char*)Bs + sw) = rb[i];
        }
        __syncthreads();
        if (kt + 1 < nk) {
#pragma unroll
            for (int i = 0; i < 4; i++) {
                ra[i] = *(const u32x4*)(A + (size_t)(m0 + srow + 32 * i) * K + (kt + 1) * 64 + ske);
                rb[i] = *(const u32x4*)(Bt + (size_t)(n0 + srow + 32 * i) * K + (kt + 1) * 64 + ske);
            }
        }
#pragma unroll
        for (int ks = 0; ks < 2; ++ks) {
            bf16x8 af[4], bg[4];
#pragma unroll
            for (int m = 0; m < 4; m++) {
                int row = wm + m * 16 + fr;
                int lin = row * 128 + ks * 64 + fg * 16;
                af[m] = *(const bf16x8*)((const char*)As + (lin ^ ((row & 7) << 4)));
            }
#pragma unroll
            for (int n = 0; n < 4; n++) {
                int col = wn + n * 16 + fr;
                int lin = col * 128 + ks * 64 + fg * 16;
                bg[n] = *(const bf16x8*)((const char*)Bs + (lin ^ ((col & 7) << 4)));
            }
#pragma unroll
            for (int m = 0; m < 4; m++)
#pragma unroll
                for (int n = 0; n < 4; n++)
                    acc[m][n] = __builtin_amdgcn_mfma_f32_16x16x32_bf16(af[m], bg[n], acc[m][n], 0, 0, 0);
        }
    }
#pragma unroll
    for (int m = 0; m < 4; m++) {
#pragma unroll
        for (int r = 0; r < 4; r++) {
            size_t row = (size_t)(m0 + wm + m * 16 + fg * 4 + r);
#pragma unroll
            for (int n = 0; n < 4; n++) {
                size_t idx = row * N + n0 + wn + n * 16 + fr;
                float v = acc[m][n][r];
                if constexpr (EPI == 0) ((float*)Cout)[idx] = v;
                else if constexpr (EPI == 4) ((unsigned short*)Cout)[idx] = f2bfu(0.5f * v * (1.f + erff(v * 0.70710678118f)));
                else ((float*)Cout)[idx] = v + aux[idx];
            }
        }
    }
}

// ---------------- fused projection GEMM: A=nx [4096][1024], Bt = WT5||INPT [9600][1024] ------
// cols 0..1023 -> RB bf16 | 1024.. -> KB | 2048.. -> VB | 3072.. silu -> GB | 4096.. expexp -> WF f32
// cols 5120..9599 -> C2B[row*4480 + col-5120] bf16
__global__ __launch_bounds__(256) void k_gemm_fused(const unsigned short* __restrict__ A, const unsigned short* __restrict__ Bt,
                                                    unsigned short* __restrict__ RB, unsigned short* __restrict__ KB,
                                                    unsigned short* __restrict__ VB, unsigned short* __restrict__ GB,
                                                    float* __restrict__ WF, unsigned short* __restrict__ C2B) {
    __shared__ alignas(16) unsigned short As[128 * 64];
    __shared__ alignas(16) unsigned short Bs[128 * 64];
    const int tid = threadIdx.x;
    const int m0 = blockIdx.y * 128, n0 = blockIdx.x * 128;
    const int wave = tid >> 6, lane = tid & 63;
    const int wm = (wave >> 1) * 64, wn = (wave & 1) * 64;
    const int fr = lane & 15, fg = lane >> 4;
    const int srow = tid >> 3;
    const int ske = (tid & 7) * 8;
    const int K = 1024;

    f32x4 acc[4][4];
#pragma unroll
    for (int m = 0; m < 4; m++)
#pragma unroll
        for (int n = 0; n < 4; n++) acc[m][n] = (f32x4)(0.f);

    u32x4 ra[4], rb[4];
#pragma unroll
    for (int i = 0; i < 4; i++) {
        ra[i] = *(const u32x4*)(A + (size_t)(m0 + srow + 32 * i) * K + ske);
        rb[i] = *(const u32x4*)(Bt + (size_t)(n0 + srow + 32 * i) * K + ske);
    }
    for (int kt = 0; kt < 16; ++kt) {
        __syncthreads();
#pragma unroll
        for (int i = 0; i < 4; i++) {
            int lin = (tid + 256 * i) * 16;
            int sw = lin ^ (((lin >> 7) & 7) << 4);
            *(u32x4*)((char*)As + sw) = ra[i];
            *(u32x4*)((char*)Bs + sw) = rb[i];
        }
        __syncthreads();
        if (kt + 1 < 16) {
#pragma unroll
            for (int i = 0; i < 4; i++) {
                ra[i] = *(const u32x4*)(A + (size_t)(m0 + srow + 32 * i) * K + (kt + 1) * 64 + ske);
                rb[i] = *(const u32x4*)(Bt + (size_t)(n0 + srow + 32 * i) * K + (kt + 1) * 64 + ske);
            }
        }
#pragma unroll
        for (int ks = 0; ks < 2; ++ks) {
            bf16x8 af[4], bg[4];
#pragma unroll
            for (int m = 0; m < 4; m++) {
                int row = wm + m * 16 + fr;
                int lin = row * 128 + ks * 64 + fg * 16;
                af[m] = *(const bf16x8*)((const char*)As + (lin ^ ((row & 7) << 4)));
            }
#pragma unroll
            for (int n = 0; n < 4; n++) {
                int col = wn + n * 16 + fr;
                int lin = col * 128 + ks * 64 + fg * 16;
                bg[n] = *(const bf16x8*)((const char*)Bs + (lin ^ ((col & 7) << 4)));
            }
#pragma unroll
            for (int m = 0; m < 4; m++)
#pragma unroll
                for (int n = 0; n < 4; n++)
                    acc[m][n] = __builtin_amdgcn_mfma_f32_16x16x32_bf16(af[m], bg[n], acc[m][n], 0, 0, 0);
        }
    }
    const int seg = n0 >> 10;  // block-uniform
#pragma unroll
    for (int m = 0; m < 4; m++) {
#pragma unroll
        for (int r = 0; r < 4; r++) {
            size_t row = (size_t)(m0 + wm + m * 16 + fg * 4 + r);
#pragma unroll
            for (int n = 0; n < 4; n++) {
                int gcol = n0 + wn + n * 16 + fr;
                float v = acc[m][n][r];
                if (n0 < 5120) {
                    size_t idx = row * 1024 + (gcol & 1023);
                    if (seg == 0) RB[idx] = f2bfu(v);
                    else if (seg == 1) KB[idx] = f2bfu(v);
                    else if (seg == 2) VB[idx] = f2bfu(v);
                    else if (seg == 3) GB[idx] = f2bfu(siluf(v));
                    else WF[idx] = expf(-expf(v));
                } else {
                    C2B[row * 4480 + (gcol - 5120)] = f2bfu(v);
                }
            }
        }
    }
}

// ---------------- RWKV sequential scan v2 (deferred reduction, k-split) ----------------
// grid (32 vblocks, 16 = bh*2+kh), 256 thr, 4 waves. Each block: 8 v, 128 k (half).
// Lane owns 4 k x 1 v. Partials to LDS; cooperative reduce per chunk. No shuffles.
#define RT 16
__global__ __launch_bounds__(256, 2) void k_rwkv_scan(const unsigned short* __restrict__ RB, const unsigned short* __restrict__ KB,
                                                      const unsigned short* __restrict__ VB, const float* __restrict__ WF,
                                                      const float* __restrict__ u,
                                                      float* __restrict__ O0, float* __restrict__ O1) {
    __shared__ float lr[RT][128], lk[RT][128], lw[RT][128];
    __shared__ float lv[RT][8];
    __shared__ float pst[RT * 292];    // [tt][w*72 + kq*9 + vv], tt stride 292
    const int tid = threadIdx.x;
    const int bh = blockIdx.y >> 1, kh = blockIdx.y & 1;
    const int b = bh >> 2, h = bh & 3;
    const int v0 = blockIdx.x * 8;
    const int wave = tid >> 6, lane = tid & 63;
    const int kq = lane >> 3, vv = lane & 7;
    const int klo = wave * 32 + kq * 4;
    const size_t baseM = (size_t)b * T_;
    float* __restrict__ OP = kh ? O1 : O0;
    float S[4] = {0.f, 0.f, 0.f, 0.f};
    float ur[4];
#pragma unroll
    for (int i = 0; i < 4; i++) ur[i] = u[h * 256 + kh * 128 + klo + i];

    for (int c = 0; c < T_ / RT; ++c) {
        __syncthreads();
        int t0 = c * RT;
#pragma unroll
        for (int it = 0; it < 2; ++it) {
            int idx = (tid + it * 256) * 4;   // 0..2044 over RT*128
            int tt = idx >> 7, k = idx & 127;
            size_t rowb = (baseM + t0 + tt) * H_ + h * 256 + kh * 128 + k;
            ushort4 r4 = *(const ushort4*)(RB + rowb);
            ushort4 k4 = *(const ushort4*)(KB + rowb);
            float4 w4 = *(const float4*)(WF + rowb);
            lr[tt][k] = bfu2f(r4.x); lr[tt][k + 1] = bfu2f(r4.y); lr[tt][k + 2] = bfu2f(r4.z); lr[tt][k + 3] = bfu2f(r4.w);
            lk[tt][k] = bfu2f(k4.x); lk[tt][k + 1] = bfu2f(k4.y); lk[tt][k + 2] = bfu2f(k4.z); lk[tt][k + 3] = bfu2f(k4.w);
            lw[tt][k] = w4.x; lw[tt][k + 1] = w4.y; lw[tt][k + 2] = w4.z; lw[tt][k + 3] = w4.w;
        }
        if (tid < RT * 8) {
            int tt = tid >> 3, xx = tid & 7;
            lv[tt][xx] = bfu2f(VB[(baseM + t0 + tt) * H_ + h * 256 + v0 + xx]);
        }
        __syncthreads();
#pragma unroll 1
        for (int tt = 0; tt < RT; ++tt) {
            float vt = lv[tt][vv];
            float4 rr = *(const float4*)&lr[tt][klo];
            float4 kk = *(const float4*)&lk[tt][klo];
            float4 ww = *(const float4*)&lw[tt][klo];
            float p0 = rr.x * S[0], p1 = rr.y * S[1];
            p0 = fmaf(rr.z, S[2], p0);
            p1 = fmaf(rr.w, S[3], p1);
            float d0 = (rr.x * ur[0]) * kk.x, d1 = (rr.y * ur[1]) * kk.y;
            d0 = fmaf(rr.z * ur[2], kk.z, d0);
            d1 = fmaf(rr.w * ur[3], kk.w, d1);
            S[0] = fmaf(S[0], ww.x, kk.x * vt);
            S[1] = fmaf(S[1], ww.y, kk.y * vt);
            S[2] = fmaf(S[2], ww.z, kk.z * vt);
            S[3] = fmaf(S[3], ww.w, kk.w * vt);
            pst[tt * 292 + wave * 72 + kq * 9 + vv] = (p0 + p1) + (d0 + d1) * vt;
        }
        __syncthreads();
        if (tid < RT * 8) {
            int tt = tid >> 3, v = tid & 7;
            float s = 0.f;
#pragma unroll
            for (int w = 0; w < 4; w++)
#pragma unroll
                for (int q = 0; q < 8; q++) s += pst[tt * 292 + w * 72 + q * 9 + v];
            OP[(baseM + t0 + tt) * H_ + h * 256 + v0 + v] = s;
        }
    }
}

// ---------------- RWKV post: per-head RMS over (o0+o1) * gn_w * g -> bf16 (in place over g) ----
__global__ __launch_bounds__(256) void k_rwkv_post(const float* __restrict__ o0, const float* __restrict__ o1,
                                                   const float* __restrict__ gn_w, unsigned short* __restrict__ g_io) {
    int m = blockIdx.x, tid = threadIdx.x;
    int wave = tid >> 6, lane = tid & 63;
    size_t base = (size_t)m * H_ + wave * 256 + lane * 4;
    int col = wave * 256 + lane * 4;
    float4 va = *(const float4*)(o0 + base);
    float4 vb = *(const float4*)(o1 + base);
    float4 v; v.x = va.x + vb.x; v.y = va.y + vb.y; v.z = va.z + vb.z; v.w = va.w + vb.w;
    float ss = v.x * v.x + v.y * v.y + v.z * v.z + v.w * v.w;
#pragma unroll
    for (int off = 32; off; off >>= 1) ss += __shfl_xor(ss, off);
    float scale = rsqrtf(ss * (1.f / 256.f) + EPS_);
    float4 gn = *(const float4*)(gn_w + col);
    ushort4 gb4 = *(const ushort4*)(g_io + base);
    ushort4 out;
    out.x = f2bfu(v.x * scale * gn.x * bfu2f(gb4.x));
    out.y = f2bfu(v.y * scale * gn.y * bfu2f(gb4.y));
    out.z = f2bfu(v.z * scale * gn.z * bfu2f(gb4.z));
    out.w = f2bfu(v.w * scale * gn.w * bfu2f(gb4.w));
    *(ushort4*)(g_io + base) = out;
}

// ---------------- causal depthwise conv(4) + bias + silu (bf16 in, split out) ----------------
__global__ __launch_bounds__(256) void k_conv(const unsigned short* __restrict__ C2B, const float* __restrict__ conv_w,
                                              const float* __restrict__ conv_b, unsigned short* __restrict__ XB,
                                              float* __restrict__ BCF) {
    int m = blockIdx.y;
    int c = blockIdx.x * 256 + threadIdx.x;  // < 2304
    int b = m >> 11, t = m & 2047;
    float acc = conv_b[c];
#pragma unroll
    for (int i = 0; i < 4; i++) {
        int tt = t - 3 + i;
        if (tt >= 0) acc = fmaf(bfu2f(C2B[((size_t)(b * T_ + tt)) * LD2 + DI + c]), conv_w[c * 4 + i], acc);
    }
    float r = siluf(acc);
    if (c < DI) XB[(size_t)m * DI + c] = f2bfu(r);
    else BCF[(size_t)m * 256 + (c - DI)] = r;
}

// ---------------- Mamba sequential scan v2 (deferred reduction, s-split) ----------------
// grid (4 d-blocks of 16 d, 2 s-halves, 64 bh), 256 thr. Lane owns 4 s x 1 d. No shuffles.
#define MT 32
__global__ __launch_bounds__(256, 2) void k_mamba_scan(const unsigned short* __restrict__ C2B, const unsigned short* __restrict__ XB,
                                                       const float* __restrict__ BCF,
                                                       const float* __restrict__ dt_bias, const float* __restrict__ A_log,
                                                       unsigned short* __restrict__ Y0, unsigned short* __restrict__ Y1) {
    __shared__ float lB[MT][64], lC[MT][64], lx[MT][16], lda[MT], ldt[MT];
    __shared__ float pst[MT * 272];   // [tt][dloc*17 + li], tt stride 272
    const int tid = threadIdx.x;
    const int d0 = blockIdx.x * 16;
    const int sh = blockIdx.y;
    const int bh = blockIdx.z;
    const int b = bh >> 5, h = bh & 31;
    const int wave = tid >> 6, lane = tid & 63;
    const int dloc = wave * 4 + (lane >> 4);  // 0..15
    const int li = lane & 15;                 // s = sh*64 + li*4 ..+3
    const size_t baseM = (size_t)b * T_;
    const float A = -expf(A_log[h]);
    const float dtb = dt_bias[h];
    unsigned short* __restrict__ YP = sh ? Y1 : Y0;
    float hS[4] = {0.f, 0.f, 0.f, 0.f};

    for (int c = 0; c < T_ / MT; ++c) {
        __syncthreads();
        int t0 = c * MT;
#pragma unroll
        for (int it = 0; it < 2; ++it) {
            int idx = (tid + it * 256) * 4;   // 0..2044 over MT*64
            int tt = idx >> 6, s = idx & 63;
            const float* src = BCF + (baseM + t0 + tt) * 256 + sh * 64 + s;
            *(float4*)&lB[tt][s] = *(const float4*)(src);
            *(float4*)&lC[tt][s] = *(const float4*)(src + 128);
        }
#pragma unroll
        for (int it = 0; it < 2; ++it) {
            int idx = tid + it * 256;          // 0..511 over MT*16
            int tt = idx >> 4, i = idx & 15;
            lx[tt][i] = bfu2f(XB[(baseM + t0 + tt) * DI + h * 64 + d0 + i]);
        }
        if (tid < MT) {
            float draw = bfu2f(C2B[(baseM + t0 + tid) * LD2 + 4352 + h]) + dtb;
            float ds = draw > 20.f ? draw : log1pf(expf(draw));
            ldt[tid] = ds;
            lda[tid] = expf(A * ds);
        }
        __syncthreads();
#pragma unroll 1
        for (int tt = 0; tt < MT; ++tt) {
            float da = lda[tt];
            float dtx = ldt[tt] * lx[tt][dloc];
            float4 Bv = *(const float4*)&lB[tt][li * 4];
            float4 Cv = *(const float4*)&lC[tt][li * 4];
            hS[0] = fmaf(hS[0], da, dtx * Bv.x);
            hS[1] = fmaf(hS[1], da, dtx * Bv.y);
            hS[2] = fmaf(hS[2], da, dtx * Bv.z);
            hS[3] = fmaf(hS[3], da, dtx * Bv.w);
            float p0 = fmaf(hS[1], Cv.y, hS[0] * Cv.x);
            float p1 = fmaf(hS[3], Cv.w, hS[2] * Cv.z);
            pst[tt * 272 + dloc * 17 + li] = p0 + p1;
        }
        __syncthreads();
        {
            int tt = tid >> 3, dl = tid & 7;
            const float* row0 = &pst[tt * 272 + dl * 17];
            const float* row1 = &pst[tt * 272 + (dl + 8) * 17];
            float s0 = 0.f, s1 = 0.f;
#pragma unroll
            for (int j = 0; j < 16; j++) { s0 += row0[j]; s1 += row1[j]; }
            size_t orow = (baseM + t0 + tt) * DI + h * 64 + d0;
            YP[orow + dl] = f2bfu(s0);
            YP[orow + dl + 8] = f2bfu(s1);
        }
    }
}

// ---------------- Mamba post: (y0+y1 + D*x) * silu(z), RMS(2048) * m_norm_w -> bf16 over y0 ----
__global__ __launch_bounds__(256) void k_mamba_post(unsigned short* __restrict__ y_io, const unsigned short* __restrict__ y1,
                                                    const unsigned short* __restrict__ XB,
                                                    const unsigned short* __restrict__ C2B, const float* __restrict__ D_m,
                                                    const float* __restrict__ mnw) {
    __shared__ float red[4];
    int m = blockIdx.x, tid = threadIdx.x;
    int j0 = tid * 8;
    const float Dv = D_m[j0 >> 6];
    ushort4 ya = *(const ushort4*)(y_io + (size_t)m * DI + j0);
    ushort4 yb = *(const ushort4*)(y_io + (size_t)m * DI + j0 + 4);
    ushort4 wa = *(const ushort4*)(y1 + (size_t)m * DI + j0);
    ushort4 wb = *(const ushort4*)(y1 + (size_t)m * DI + j0 + 4);
    ushort4 xa = *(const ushort4*)(XB + (size_t)m * DI + j0);
    ushort4 xb = *(const ushort4*)(XB + (size_t)m * DI + j0 + 4);
    ushort4 za = *(const ushort4*)(C2B + (size_t)m * LD2 + j0);
    ushort4 zb = *(const ushort4*)(C2B + (size_t)m * LD2 + j0 + 4);
    float yv[8] = {bfu2f(ya.x) + bfu2f(wa.x), bfu2f(ya.y) + bfu2f(wa.y), bfu2f(ya.z) + bfu2f(wa.z), bfu2f(ya.w) + bfu2f(wa.w),
                   bfu2f(yb.x) + bfu2f(wb.x), bfu2f(yb.y) + bfu2f(wb.y), bfu2f(yb.z) + bfu2f(wb.z), bfu2f(yb.w) + bfu2f(wb.w)};
    float xv[8] = {bfu2f(xa.x), bfu2f(xa.y), bfu2f(xa.z), bfu2f(xa.w), bfu2f(xb.x), bfu2f(xb.y), bfu2f(xb.z), bfu2f(xb.w)};
    float zv[8] = {bfu2f(za.x), bfu2f(za.y), bfu2f(za.z), bfu2f(za.w), bfu2f(zb.x), bfu2f(zb.y), bfu2f(zb.z), bfu2f(zb.w)};
    float val[8];
    float ss = 0.f;
#pragma unroll
    for (int i = 0; i < 8; i++) {
        float v = (yv[i] + Dv * xv[i]) * siluf(zv[i]);
        val[i] = v;
        ss += v * v;
    }
#pragma unroll
    for (int off = 32; off; off >>= 1) ss += __shfl_xor(ss, off);
    if ((tid & 63) == 0) red[tid >> 6] = ss;
    __syncthreads();
    float scale = rsqrtf((red[0] + red[1] + red[2] + red[3]) * (1.f / 2048.f) + EPS_);
    ushort4 oa, ob;
    oa.x = f2bfu(val[0] * scale * mnw[j0 + 0]); oa.y = f2bfu(val[1] * scale * mnw[j0 + 1]);
    oa.z = f2bfu(val[2] * scale * mnw[j0 + 2]); oa.w = f2bfu(val[3] * scale * mnw[j0 + 3]);
    ob.x = f2bfu(val[4] * scale * mnw[j0 + 4]); ob.y = f2bfu(val[5] * scale * mnw[j0 + 5]);
    ob.z = f2bfu(val[6] * scale * mnw[j0 + 6]); ob.w = f2bfu(val[7] * scale * mnw[j0 + 7]);
    *(ushort4*)(y_io + (size_t)m * DI + j0) = oa;
    *(ushort4*)(y_io + (size_t)m * DI + j0 + 4) = ob;
}

// ---------------- gate + mix + residual + RMS(ffn_ln) -> x1 f32, nx2 bf16 ----------------
__global__ __launch_bounds__(256) void k_mix(const float* __restrict__ x, const float* __restrict__ o_r,
                                             const float* __restrict__ o_m, const float* __restrict__ gw,
                                             const float* __restrict__ gb, const float* __restrict__ flnw,
                                             float* __restrict__ x1, unsigned short* __restrict__ nx2) {
    __shared__ float red[4];
    int m = blockIdx.x, tid = threadIdx.x;
    size_t base = (size_t)m * H_ + tid * 4;
    float4 orv = *(const float4*)(o_r + base);
    float4 omv = *(const float4*)(o_m + base);
    float4 xv = *(const float4*)(x + base);
    float4 g1 = *(const float4*)(gw + tid * 4);
    float4 g2 = *(const float4*)(gw + 1024 + tid * 4);
    float ps = orv.x * g1.x + orv.y * g1.y + orv.z * g1.z + orv.w * g1.w
             + omv.x * g2.x + omv.y * g2.y + omv.z * g2.z + omv.w * g2.w;
#pragma unroll
    for (int off = 32; off; off >>= 1) ps += __shfl_xor(ps, off);
    if ((tid & 63) == 0) red[tid >> 6] = ps;
    __syncthreads();
    float g = 1.f / (1.f + expf(-(red[0] + red[1] + red[2] + red[3] + gb[0])));
    float4 xo;
    xo.x = xv.x + g * orv.x + (1.f - g) * omv.x;
    xo.y = xv.y + g * orv.y + (1.f - g) * omv.y;
    xo.z = xv.z + g * orv.z + (1.f - g) * omv.z;
    xo.w = xv.w + g * orv.w + (1.f - g) * omv.w;
    *(float4*)(x1 + base) = xo;
    float ss = xo.x * xo.x + xo.y * xo.y + xo.z * xo.z + xo.w * xo.w;
#pragma unroll
    for (int off = 32; off; off >>= 1) ss += __shfl_xor(ss, off);
    __syncthreads();
    if ((tid & 63) == 0) red[tid >> 6] = ss;
    __syncthreads();
    float scale = rsqrtf((red[0] + red[1] + red[2] + red[3]) * (1.f / 1024.f) + EPS_);
    float4 wv = *(const float4*)(flnw + tid * 4);
    ushort4 o;
    o.x = f2bfu(xo.x * scale * wv.x); o.y = f2bfu(xo.y * scale * wv.y);
    o.z = f2bfu(xo.z * scale * wv.z); o.w = f2bfu(xo.w * scale * wv.w);
    *(ushort4*)(nx2 + base) = o;
}

extern "C" void kernel_launch(void* const* d_in, const int* in_sizes, int n_in,
                              void* d_out, int out_size, void* d_ws, size_t ws_size,
                              hipStream_t stream) {
    const float* x = (const float*)d_in[0];
    const float* ln_w = (const float*)d_in[1];
    const float* r_w = (const float*)d_in[2];
    const float* k_w = (const float*)d_in[3];
    const float* v_w = (const float*)d_in[4];
    const float* g_w = (const float*)d_in[5];
    const float* dw_w = (const float*)d_in[6];
    const float* u = (const float*)d_in[7];
    const float* gn_w = (const float*)d_in[8];
    const float* o_w = (const float*)d_in[9];
    const float* in_proj = (const float*)d_in[10];
    const float* conv_w = (const float*)d_in[11];
    const float* conv_b = (const float*)d_in[12];
    const float* dt_bias = (const float*)d_in[13];
    const float* A_log = (const float*)d_in[14];
    const float* D_m = (const float*)d_in[15];
    const float* m_norm_w = (const float*)d_in[16];
    const float* out_proj = (const float*)d_in[17];
    const float* gate_w = (const float*)d_in[18];
    const float* gate_b = (const float*)d_in[19];
    const float* ffn_ln_w = (const float*)d_in[20];
    const float* ffn_w1 = (const float*)d_in[21];
    const float* ffn_w2 = (const float*)d_in[22];
    (void)in_sizes; (void)n_in;

    // ---- explicit workspace layout (peak ~184 MiB) ----
    const size_t NEEDED = 192675840ull;
    if (ws_size < NEEDED) {
        hipMemsetAsync(d_out, 0, (size_t)out_size * 4, stream);
        return;
    }
    char* ws = (char*)d_ws;
    unsigned short* WT5 = (unsigned short*)(ws + 0);            // [5120][1024] bf16 (r|k|v|g|dw ^T)
    unsigned short* INPT = (unsigned short*)(ws + 10485760);    // [4480][1024] bf16 (contiguous after WT5)
    unsigned short* F1T = (unsigned short*)(ws + 0);            // overlay after fused GEMM
    unsigned short* F2T = (unsigned short*)(ws + 10485760);     // overlay
    unsigned short* OWT = (unsigned short*)(ws + 19660800);     // [1024][1024] bf16
    unsigned short* OPT = (unsigned short*)(ws + 21757952);     // [1024][2048] bf16
    unsigned short* NXB = (unsigned short*)(ws + 25952256);     // [4096][1024] bf16 nx; later nx2
    unsigned short* RB = (unsigned short*)(ws + 34340864);      // [4096][1024] bf16
    unsigned short* KB = (unsigned short*)(ws + 42729472);      // [4096][1024] bf16
    unsigned short* VB = (unsigned short*)(ws + 51118080);      // [4096][1024] bf16
    unsigned short* GB = (unsigned short*)(ws + 59506688);      // [4096][1024] bf16 silu(g) -> o*gn*g
    float* WF = (float*)(ws + 67895296);                        // [4096][1024] f32 decay; later Y1
    unsigned short* Y1 = (unsigned short*)(ws + 67895296);      // overlay WF (dead after rwkv_scan): [4096][2048] bf16
    float* OM = (float*)(ws + 34340864);                        // overlay RB/KB (dead after rwkv_scan): o_m f32
    unsigned short* MIDB = (unsigned short*)(ws + 51118080);    // overlay VB/GB/WF: [4096][4096] bf16
    unsigned short* C2B = (unsigned short*)(ws + 84672512);     // [4096][4480] bf16
    unsigned short* XB = (unsigned short*)(ws + 121372672);     // [4096][2048] bf16 conv-x
    float* BCF = (float*)(ws + 138149888);                      // [4096][256] f32 conv-B|C
    float* OBUF = (float*)(ws + 142344192);                     // [4096][1024] f32 rwkv o half0; later x1
    float* ORB = (float*)(ws + 159121408);                      // [4096][1024] f32 rwkv o half1; later o_r; later ffn out
    unsigned short* YB = (unsigned short*)(ws + 175898624);     // [4096][2048] bf16 y half0; in-place gated-rms
    // end: 192,675,840

    dim3 blk(256);
    k_rms1024<<<M_, blk, 0, stream>>>(x, ln_w, NXB);
    // weight transposes (fp32 [K,N] -> bf16 [NP,K])
    k_transpose<<<dim3(32, 32), blk, 0, stream>>>(r_w, WT5 + 0ull * 1048576, 1024, 1024, 1024);
    k_transpose<<<dim3(32, 32), blk, 0, stream>>>(k_w, WT5 + 1ull * 1048576, 1024, 1024, 1024);
    k_transpose<<<dim3(32, 32), blk, 0, stream>>>(v_w, WT5 + 2ull * 1048576, 1024, 1024, 1024);
    k_transpose<<<dim3(32, 32), blk, 0, stream>>>(g_w, WT5 + 3ull * 1048576, 1024, 1024, 1024);
    k_transpose<<<dim3(32, 32), blk, 0, stream>>>(dw_w, WT5 + 4ull * 1048576, 1024, 1024, 1024);
    k_transpose<<<dim3(140, 32), blk, 0, stream>>>(in_proj, INPT, 1024, 4384, 4480);
    k_transpose<<<dim3(32, 32), blk, 0, stream>>>(o_w, OWT, 1024, 1024, 1024);
    k_transpose<<<dim3(32, 64), blk, 0, stream>>>(out_proj, OPT, 2048, 1024, 1024);
    // all 6 projections in ONE GEMM (Bt = WT5||INPT = [9600][1024])
    k_gemm_fused<<<dim3(75, 32), blk, 0, stream>>>(NXB, WT5, RB, KB, VB, GB, WF, C2B);
    // FFN weight transposes AFTER fused GEMM (overlay WT5/INPT region)
    k_transpose<<<dim3(128, 32), blk, 0, stream>>>(ffn_w1, F1T, 1024, 4096, 4096);
    k_transpose<<<dim3(32, 128), blk, 0, stream>>>(ffn_w2, F2T, 4096, 1024, 1024);
    // conv + scans (rwkv first: frees WF region for Y1)
    k_conv<<<dim3(9, M_), blk, 0, stream>>>(C2B, conv_w, conv_b, XB, BCF);
    k_rwkv_scan<<<dim3(32, 16), blk, 0, stream>>>(RB, KB, VB, WF, u, OBUF, ORB);
    k_mamba_scan<<<dim3(4, 2, 64), blk, 0, stream>>>(C2B, XB, BCF, dt_bias, A_log, YB, Y1);
    // rwkv output path
    k_rwkv_post<<<M_, blk, 0, stream>>>(OBUF, ORB, gn_w, GB);
    k_gemm<0><<<dim3(8, 32), blk, 0, stream>>>(GB, OWT, ORB, nullptr, 4096, 1024, 1024);
    // mamba output path
    k_mamba_post<<<M_, blk, 0, stream>>>(YB, Y1, XB, C2B, D_m, m_norm_w);
    k_gemm<0><<<dim3(8, 32), blk, 0, stream>>>(YB, OPT, OM, nullptr, 4096, 1024, 2048);
    // gate + residual + ffn rms (x1 over OBUF, nx2 over NXB)
    k_mix<<<M_, blk, 0, stream>>>(x, ORB, OM, gate_w, gate_b, ffn_ln_w, OBUF, NXB);
    // FFN: gelu fused; ffn2 fuses the final residual add -> d_out
    k_gemm<4><<<dim3(32, 32), blk, 0, stream>>>(NXB, F1T, MIDB, nullptr, 4096, 4096, 1024);
    k_gemm<5><<<dim3(8, 32), blk, 0, stream>>>(MIDB, F2T, (float*)d_out, OBUF, 4096, 1024, 4096);
}